// Round 8
// baseline (491.852 us; speedup 1.0000x reference)
//
#include <hip/hip_runtime.h>
#include <stdint.h>

typedef unsigned long long u64;
typedef unsigned int u32;
typedef float v2f __attribute__((ext_vector_type(2)));

#define NB 32     // batches
#define NP 8192   // points per batch
#define NG 256    // FPS centers
#define NK 32     // neighbors per center

// Exact IEEE ops (block FMA contraction so we bit-match the numpy reference):
// d = ((dx*dx) + (dy*dy)) + (dz*dz)
__device__ __forceinline__ float dist3(float dx, float dy, float dz) {
    return __fadd_rn(__fadd_rn(__fmul_rn(dx, dx), __fmul_rn(dy, dy)), __fmul_rn(dz, dz));
}

// ---- DPP wave reductions (VALU-only, no LDS pipe) ----------------------------
#define DPP_STEP(v, ctrl, rmask) __builtin_amdgcn_update_dpp((int)(v), (int)(v), (ctrl), (rmask), 0xf, false)

__device__ __forceinline__ u32 wave_max_u32(u32 v) {
    u32 o;
    o = (u32)DPP_STEP(v, 0x111, 0xf); v = (o > v) ? o : v;  // row_shr:1
    o = (u32)DPP_STEP(v, 0x112, 0xf); v = (o > v) ? o : v;  // row_shr:2
    o = (u32)DPP_STEP(v, 0x114, 0xf); v = (o > v) ? o : v;  // row_shr:4
    o = (u32)DPP_STEP(v, 0x118, 0xf); v = (o > v) ? o : v;  // row_shr:8
    o = (u32)DPP_STEP(v, 0x142, 0xa); v = (o > v) ? o : v;  // row_bcast:15
    o = (u32)DPP_STEP(v, 0x143, 0xc); v = (o > v) ? o : v;  // row_bcast:31
    return (u32)__builtin_amdgcn_readlane((int)v, 63);
}

__device__ __forceinline__ u32 wave_min_u32(u32 v) {
    u32 o;
    o = (u32)DPP_STEP(v, 0x111, 0xf); v = (o < v) ? o : v;
    o = (u32)DPP_STEP(v, 0x112, 0xf); v = (o < v) ? o : v;
    o = (u32)DPP_STEP(v, 0x114, 0xf); v = (o < v) ? o : v;
    o = (u32)DPP_STEP(v, 0x118, 0xf); v = (o < v) ? o : v;
    o = (u32)DPP_STEP(v, 0x142, 0xa); v = (o < v) ? o : v;
    o = (u32)DPP_STEP(v, 0x143, 0xc); v = (o < v) ? o : v;
    return (u32)__builtin_amdgcn_readlane((int)v, 63);
}

// float4 component by compile-time index (folds under full unroll)
#define F4C(v, c) ((c) == 0 ? (v).x : ((c) == 1 ? (v).y : ((c) == 2 ? (v).z : (v).w)))

// ---------------------------------------------------------------------------
// Kernel 1: farthest point sampling. One block (512 threads, 8 waves) per
// batch. The 48 floats/thread of point state live in LDS as an explicit
// per-thread backing store (the register allocator refuses to keep them:
// VGPR_Count=44 + zero scratch across r2-r7 => it rematerializes the global
// loads every iteration, ~96KB/block/iter through L1/L2). Layout: 13 float4
// slots per thread (12 used): bank-group (5t+s)%8 is a permutation per
// 8-thread run -> conflict-free ds_read_b128. The opaque asm on the LDS
// offset each iteration blocks store-forwarding AND loop hoisting.
// Next centroid comes from the winner lane's registers via LDS (wkey+wcoord,
// parity double-buffered) -- no more dependent L2 fetch on the critical path.
// Bit-exact vs reference: dist = min(dist, ((dx*dx)+(dy*dy))+(dz*dz));
// argmax = first index of max (ties -> larger NP-1-idx = smaller idx).
// ---------------------------------------------------------------------------
__global__ __launch_bounds__(512, 2) void fps_kernel(const float* __restrict__ xyz,
                                                     float* __restrict__ out)
{
    #pragma clang fp contract(off)
    __shared__ float4 pbuf[512 * 13];      // 106,496 B
    __shared__ u64 wkey[2][8];
    __shared__ float wcoord[2][8][4];

    const int b = blockIdx.x;
    const int t = threadIdx.x;
    const int wid = t >> 6;

    const float* base = xyz + (size_t)b * NP * 3;

    // ---- stage 16 points/thread into LDS, SoA per thread ----
    {
        const float4* src = reinterpret_cast<const float4*>(base) + t * 12;
        float4 f[12];
        #pragma unroll
        for (int i = 0; i < 12; ++i) f[i] = src[i];
        float fl[48];
        #pragma unroll
        for (int i = 0; i < 12; ++i) {
            fl[4*i] = f[i].x; fl[4*i+1] = f[i].y; fl[4*i+2] = f[i].z; fl[4*i+3] = f[i].w;
        }
        float4* myb = pbuf + t * 13;
        // slots 0..3 = x of pts 0..15, 4..7 = y, 8..11 = z
        #pragma unroll
        for (int s = 0; s < 4; ++s)
            myb[s] = (float4){fl[3*(4*s+0)], fl[3*(4*s+1)], fl[3*(4*s+2)], fl[3*(4*s+3)]};
        #pragma unroll
        for (int s = 0; s < 4; ++s)
            myb[4+s] = (float4){fl[3*(4*s+0)+1], fl[3*(4*s+1)+1], fl[3*(4*s+2)+1], fl[3*(4*s+3)+1]};
        #pragma unroll
        for (int s = 0; s < 4; ++s)
            myb[8+s] = (float4){fl[3*(4*s+0)+2], fl[3*(4*s+1)+2], fl[3*(4*s+2)+2], fl[3*(4*s+3)+2]};
    }

    v2f dist[8];
    #pragma unroll
    for (int j = 0; j < 8; ++j) dist[j] = (v2f){1e10f, 1e10f};

    // first centroid = point 0
    float cx, cy, cz;
    {
        float4 f0 = *reinterpret_cast<const float4*>(base);
        cx = f0.x; cy = f0.y; cz = f0.z;
        if (t == 0) {
            float* o = out + (size_t)b * NG * 3;
            o[0] = cx; o[1] = cy; o[2] = cz;
        }
    }
    __syncthreads();   // make pbuf contents architectural (no store-forwarding)

    u32 mof = (u32)(t * 13 * 16);          // LDS byte offset of this thread's block

    for (int g = 0; g < NG - 1; ++g) {
        asm volatile("" : "+v"(mof));      // opaque: loads can't hoist/forward
        const float4* myb = reinterpret_cast<const float4*>(
            reinterpret_cast<const char*>(pbuf) + mof);
        float4 S[12];
        #pragma unroll
        for (int s = 0; s < 12; ++s) S[s] = myb[s];

        const v2f cvx = (v2f){cx, cx};
        const v2f cvy = (v2f){cy, cy};
        const v2f cvz = (v2f){cz, cz};
        float bestd = -1.0f;
        u32 bestj = 0;
        #pragma unroll
        for (int j = 0; j < 8; ++j) {
            v2f pxp = (j & 1) ? (v2f){S[j>>1].z,     S[j>>1].w}     : (v2f){S[j>>1].x,     S[j>>1].y};
            v2f pyp = (j & 1) ? (v2f){S[4+(j>>1)].z, S[4+(j>>1)].w} : (v2f){S[4+(j>>1)].x, S[4+(j>>1)].y};
            v2f pzp = (j & 1) ? (v2f){S[8+(j>>1)].z, S[8+(j>>1)].w} : (v2f){S[8+(j>>1)].x, S[8+(j>>1)].y};
            v2f dx = pxp - cvx;
            v2f dy = pyp - cvy;
            v2f dz = pzp - cvz;
            v2f q  = (dx * dx + dy * dy) + dz * dz;   // contract(off): mul,mul,add,mul,add
            float d0 = fminf(dist[j].x, q.x);
            float d1 = fminf(dist[j].y, q.y);
            dist[j].x = d0; dist[j].y = d1;
            bool g0 = d0 > bestd;               // strict >, ascending => first max
            bestd = g0 ? d0 : bestd;
            bestj = g0 ? (u32)(2*j) : bestj;
            bool g1 = d1 > bestd;
            bestd = g1 ? d1 : bestd;
            bestj = g1 ? (u32)(2*j+1) : bestj;
        }
        // dist >= 0 -> float bits order-monotone
        u32 hi = __float_as_uint(bestd);
        u32 lo = (u32)(NP - 1 - (t * 16 + (int)bestj));   // larger = smaller idx
        u32 mh = wave_max_u32(hi);
        u32 cl = (hi == mh) ? lo : 0u;
        u32 ml = wave_max_u32(cl);
        if (hi == mh && lo == ml) {
            // unique winner lane of this wave: publish key + its coords
            float wx = 0.f, wy = 0.f, wz = 0.f;
            #pragma unroll
            for (int p = 0; p < 16; ++p) {
                if (bestj == (u32)p) {
                    wx = F4C(S[p >> 2],     p & 3);
                    wy = F4C(S[4 + (p>>2)], p & 3);
                    wz = F4C(S[8 + (p>>2)], p & 3);
                }
            }
            wkey[g & 1][wid] = ((u64)mh << 32) | (u64)ml;
            wcoord[g & 1][wid][0] = wx;
            wcoord[g & 1][wid][1] = wy;
            wcoord[g & 1][wid][2] = wz;
        }
        __syncthreads();

        u64 wk = wkey[g & 1][0];
        int wsel = 0;
        #pragma unroll
        for (int w = 1; w < 8; ++w) {
            u64 o = wkey[g & 1][w];
            bool gt = o > wk;
            wk = gt ? o : wk;
            wsel = gt ? w : wsel;
        }
        cx = wcoord[g & 1][wsel][0];
        cy = wcoord[g & 1][wsel][1];
        cz = wcoord[g & 1][wsel][2];
        if (t == 0) {
            float* o = out + ((size_t)b * NG + g + 1) * 3;
            o[0] = cx; o[1] = cy; o[2] = cz;
        }
    }
}

// ---------------------------------------------------------------------------
// Kernel 2: 32-NN mean per (batch, center). One WAVE per task, ZERO LDS.
// Lane assignment is interleaved: idx = c*256 + k*64 + lane, so each float3
// load's wave footprint is one contiguous 768B span (~12 cache lines, the
// minimum) instead of 64 lane-private lines. 2-chunk register ping-pong
// (named sets a*/b*, all indices static) hides VMEM latency under compute.
// Extraction: DPP u32-min on dist bits, then DPP min over tied indices
// (exact (dist,idx) order = lax.top_k's stable order). Wave-collective exact
// rescan (filter pk > per-lane L; L==0 <=> never extracted) if a lane's
// 4-entry list empties (~1%/task).
// ---------------------------------------------------------------------------
__device__ __forceinline__ void insert4(u64 pk, u64& t0, u64& t1, u64& t2, u64& t3) {
    if (pk < t3) {
        t3 = pk;
        if (t3 < t2) { u64 tmp = t2; t2 = t3; t3 = tmp; }
        if (t2 < t1) { u64 tmp = t1; t1 = t2; t2 = tmp; }
        if (t1 < t0) { u64 tmp = t0; t0 = t1; t1 = tmp; }
    }
}

__device__ __forceinline__ float3 ld3(const float* p) {
    return *reinterpret_cast<const float3*>(p);
}

#define KPROC(P, IDX) { \
    float nx = (P).x, ny = (P).y, nz = (P).z; \
    float dotv = __fadd_rn(__fadd_rn(__fmul_rn(cx,nx), __fmul_rn(cy,ny)), __fmul_rn(cz,nz)); \
    float n2   = dist3(nx, ny, nz); \
    float d    = __fadd_rn(__fsub_rn(s2, __fmul_rn(2.0f, dotv)), n2); \
    u32 u  = __float_as_uint(d); \
    u32 kk = u ^ (u32)(((int)u >> 31) | 0x80000000); \
    u64 pk = ((u64)kk << 32) | (u64)(u32)(IDX); \
    if (!useL || pk > L) insert4(pk, t0, t1, t2, t3); }

__device__ __forceinline__ void scan_top4(const float* __restrict__ pts,
                                          float cx, float cy, float cz, float s2,
                                          u64 L, bool useL, int lane,
                                          u64& t0, u64& t1, u64& t2, u64& t3)
{
    #pragma clang fp contract(off)
    t0 = t1 = t2 = t3 = ~0ull;
    const float* lp = pts + lane * 3;

    float3 a0, a1, a2, a3, b0, b1, b2, b3;
    a0 = ld3(lp);       a1 = ld3(lp + 192);
    a2 = ld3(lp + 384); a3 = ld3(lp + 576);

    for (int c = 0; c < 32; c += 2) {
        const float* q1 = lp + (size_t)(c + 1) * 768;
        b0 = ld3(q1);       b1 = ld3(q1 + 192);
        b2 = ld3(q1 + 384); b3 = ld3(q1 + 576);

        KPROC(a0, c*256 +       lane);
        KPROC(a1, c*256 +  64 + lane);
        KPROC(a2, c*256 + 128 + lane);
        KPROC(a3, c*256 + 192 + lane);

        if (c + 2 < 32) {
            const float* q2 = lp + (size_t)(c + 2) * 768;
            a0 = ld3(q2);       a1 = ld3(q2 + 192);
            a2 = ld3(q2 + 384); a3 = ld3(q2 + 576);
        }

        KPROC(b0, (c+1)*256 +       lane);
        KPROC(b1, (c+1)*256 +  64 + lane);
        KPROC(b2, (c+1)*256 + 128 + lane);
        KPROC(b3, (c+1)*256 + 192 + lane);
    }
}

__global__ __launch_bounds__(256) void knn_kernel(const float* __restrict__ xyz,
                                                  float* __restrict__ out)
{
    const int t    = threadIdx.x;
    const int lane = t & 63;
    const int wid  = t >> 6;
    const int task = blockIdx.x * 4 + wid;   // 0..8191
    const int b    = task >> 8;
    const int g    = task & 255;

    const float* cptr = out + ((size_t)b * NG + g) * 3;   // centers from fps_kernel
    const float cx = cptr[0], cy = cptr[1], cz = cptr[2];
    const float s2 = dist3(cx, cy, cz);

    const float* pts = xyz + (size_t)b * NP * 3;

    u64 t0, t1, t2, t3;
    scan_top4(pts, cx, cy, cz, s2, 0ull, false, lane, t0, t1, t2, t3);
    int cnt = 4;
    u64 L = 0;
    u32 myWin = 0;

    for (int round = 0; round < NK; ++round) {
        if (__ballot(cnt == 0) != 0ull) {
            // wave-collective exact refill; per-lane filter pk > L reproduces
            // each lane's unextracted state (verified in round 7).
            scan_top4(pts, cx, cy, cz, s2, L, L != 0ull, lane, t0, t1, t2, t3);
            cnt = 4;
        }
        u32 hi0 = (u32)(t0 >> 32);
        u32 lo0 = (u32)(t0 & 0xFFFFFFFFull);
        u32 mh = wave_min_u32(hi0);
        u32 cl = (hi0 == mh) ? lo0 : 0xFFFFFFFFu;
        u32 ml = wave_min_u32(cl);            // smallest tied index (matches top_k)
        u64 w  = ((u64)mh << 32) | (u64)ml;
        if (t0 == w) {                        // unique owner (idx packed in key)
            L = w;
            t0 = t1; t1 = t2; t2 = t3; t3 = ~0ull;
            --cnt;
        }
        if (lane == round) myWin = ml;
    }

    float sx = 0.f, sy = 0.f, sz = 0.f;
    if (lane < NK) {
        const float* p = xyz + ((size_t)b * NP + myWin) * 3;
        sx = p[0]; sy = p[1]; sz = p[2];
    }
    #pragma unroll
    for (int m = 32; m >= 1; m >>= 1) {
        sx += __shfl_xor(sx, m, 64);
        sy += __shfl_xor(sy, m, 64);
        sz += __shfl_xor(sz, m, 64);
    }
    if (lane == 0) {
        float* o = out + (size_t)NB * NG * 3 + ((size_t)b * NG + g) * 3;
        const float inv = 1.0f / 32.0f;   // /32 exact (power of 2)
        o[0] = sx * inv; o[1] = sy * inv; o[2] = sz * inv;
    }
}

extern "C" void kernel_launch(void* const* d_in, const int* in_sizes, int n_in,
                              void* d_out, int out_size, void* d_ws, size_t ws_size,
                              hipStream_t stream)
{
    const float* xyz = (const float*)d_in[0];
    float* out = (float*)d_out;

    hipLaunchKernelGGL(fps_kernel, dim3(NB), dim3(512), 0, stream, xyz, out);

    const int tasks  = NB * NG;            // 8192
    const int blocks = tasks / 4;          // 4 waves (tasks) per 256-thread block
    hipLaunchKernelGGL(knn_kernel, dim3(blocks), dim3(256), 0, stream, xyz, out);
}